// Round 4
// baseline (271.107 us; speedup 1.0000x reference)
//
#include <hip/hip_runtime.h>
#include <stdint.h>

typedef __bf16 bf16x8 __attribute__((ext_vector_type(8)));
typedef float f32x4 __attribute__((ext_vector_type(4)));

__device__ __forceinline__ unsigned int f2bf(float f) {
  unsigned int u = __float_as_uint(f);
  return (u + 0x7fffu + ((u >> 16) & 1u)) >> 16;  // RNE
}
__device__ __forceinline__ unsigned int pack2(float a, float b) {
  return f2bf(a) | (f2bf(b) << 16);
}

// In-register 16-point FWHT (4 stages, fully unrolled)
__device__ __forceinline__ void fwht16(float v[16]) {
#pragma unroll
  for (int s = 0; s < 4; ++s) {
    const int h = 1 << s;
#pragma unroll
    for (int i = 0; i < 16; ++i) {
      if (!(i & h)) {
        float a = v[i], b = v[i ^ h];
        v[i] = a + b;
        v[i ^ h] = a - b;
      }
    }
  }
}

#define LP(i) ((i) + ((i) >> 5))  // padded LDS index: +1 float per 32

// ---------------------------------------------------------------------------
// K1+K2 merged ("prep"): blocks [0,4096) do per-row FWHT(4096)(x*SU)*(1/64)
// -> bf16 ; blocks [4096,12288) decompress W[m][k] = grid[Qidxs[m][k/8]][k%8].
// ---------------------------------------------------------------------------
__global__ void __launch_bounds__(256) k_prep(const float* __restrict__ X,
                                              const float* __restrict__ SU,
                                              unsigned short* __restrict__ Xh,
                                              const int* __restrict__ Qidxs,
                                              const float* __restrict__ G,
                                              unsigned short* __restrict__ Wh) {
  __shared__ float lds[4224];  // 4096 + 128 pad (unused by decompress blocks)
  const int t = threadIdx.x;
  if (blockIdx.x >= 4096) {
    // ---- decompress ----
    int e = (blockIdx.x - 4096) * 256 + t;
    int idx = Qidxs[e];
    const float4* g = (const float4*)(G + (size_t)idx * 8);
    float4 a = g[0], b = g[1];
    uint4 o;
    o.x = pack2(a.x, a.y);
    o.y = pack2(a.z, a.w);
    o.z = pack2(b.x, b.y);
    o.w = pack2(b.z, b.w);
    ((uint4*)Wh)[e] = o;
    return;
  }
  // ---- FWHT-in ----
  const size_t row = blockIdx.x;
  const float4* xr = (const float4*)(X + row * 4096);
  const float4* su = (const float4*)SU;
  float v[16];
#pragma unroll
  for (int q = 0; q < 4; ++q) {
    float4 a = xr[4 * t + q], s = su[4 * t + q];
    v[4 * q + 0] = a.x * s.x;
    v[4 * q + 1] = a.y * s.y;
    v[4 * q + 2] = a.z * s.z;
    v[4 * q + 3] = a.w * s.w;
  }
  fwht16(v);  // bits 0-3
#pragma unroll
  for (int q = 0; q < 4; ++q) {
    int i0 = 16 * t + 4 * q;
    *(float4*)&lds[LP(i0)] = make_float4(v[4 * q], v[4 * q + 1], v[4 * q + 2], v[4 * q + 3]);
  }
  __syncthreads();
  const int b = ((t >> 4) << 8) | (t & 15);
#pragma unroll
  for (int j = 0; j < 16; ++j) { int i = b + 16 * j; v[j] = lds[LP(i)]; }
  fwht16(v);  // bits 4-7
#pragma unroll
  for (int j = 0; j < 16; ++j) { int i = b + 16 * j; lds[LP(i)] = v[j]; }
  __syncthreads();
#pragma unroll
  for (int j = 0; j < 16; ++j) { int i = t + 256 * j; v[j] = lds[LP(i)]; }
  fwht16(v);  // bits 8-11
  unsigned short* orow = Xh + row * 4096;
#pragma unroll
  for (int j = 0; j < 16; ++j)
    orow[t + 256 * j] = (unsigned short)f2bf(v[j] * 0.015625f);
}

// ---------------------------------------------------------------------------
// K3: GEMM C = A @ B^T (both bf16 [4096][4096], K-major), fp32 out.
// 256x256 tile, BK=64, 8 waves (2Mx4N). 4-phase groups, 3-buffer A-fragment
// rotation, ONE vmcnt(4) per K-tile. R4: ALL sched_barrier(0) pins REMOVED
// (m141: order-pinning defeats compiler scheduling; m201 template has none).
// Correctness without them: s_barrier fences LDS/VMEM motion (WAR intact);
// WAITV4 has a "memory" clobber; MFMA deps are compiler-tracked plain loads
// (counted lgkmcnt auto-inserted).
//
// vmcnt ledger (per wave, 2 loads/stage-call; group g, buf p=g&1):
//   entry: 4 outstanding = B(g+1)
//   ph0 +A(g+1)h0 -> 6 ; ph1 +A(g+1)h1 -> 8
//   ph2 +B(g+2)h0 -> 10; ph3 +B(g+2)h1 -> 12; vmcnt(4) retires 8 oldest
//     = B(g+1)(4) + A(g+1)(4); exit with 4 = B(g+2).
// WAR: stage A(g+1)->buf p^1 (ph0/1): prior readers drained before group
//   g-1's closing barrier. stage B(g+2)->buf p (ph2/3): prior readers are
//   group-g ph0 bq reads, drained before ph0's closing barrier.
// ---------------------------------------------------------------------------
__device__ __forceinline__ void gl2lds16(const unsigned short* g, unsigned short* l) {
  __builtin_amdgcn_global_load_lds(
      (const __attribute__((address_space(1))) void*)g,
      (__attribute__((address_space(3))) void*)l, 16, 0, 0);
}

#define BARX() __builtin_amdgcn_s_barrier()
#define WAITV4() asm volatile("s_waitcnt vmcnt(4)" ::: "memory")

#define RD_A(dst, mm)                                                          \
  _Pragma("unroll") for (int kh = 0; kh < 2; ++kh)                             \
      dst[kh] = *(const bf16x8*)&sAp[(((wr) << 7) + ((mm) << 4) + frow) * 64 + \
                                     ((((kh << 2) + jb) ^ sw) << 3)];
#define RD_B()                                                                 \
  _Pragma("unroll") for (int n = 0; n < 4; ++n)                                \
      _Pragma("unroll") for (int kh = 0; kh < 2; ++kh)                         \
          bq[n][kh] = *(const bf16x8*)&sBp[(((wc) << 6) + (n << 4) + frow) * 64 + \
                                           ((((kh << 2) + jb) ^ sw) << 3)];
#define MF(mm, buf)                                                            \
  _Pragma("unroll") for (int n = 0; n < 4; ++n)                                \
      _Pragma("unroll") for (int kh = 0; kh < 2; ++kh)                         \
          acc[(mm)][n] = __builtin_amdgcn_mfma_f32_16x16x32_bf16(              \
              buf[kh], bq[n][kh], acc[(mm)][n], 0, 0, 0);

__global__ void __launch_bounds__(512, 2)
k_gemm_bt(const unsigned short* __restrict__ A,
          const unsigned short* __restrict__ B,
          float* __restrict__ C) {
  const int K = 4096, N = 4096;
  __shared__ unsigned short sA[2][256 * 64];
  __shared__ unsigned short sB[2][256 * 64];
  const int tid = threadIdx.x;
  const int lane = tid & 63;
  const int wave = tid >> 6;
  const int wr = wave >> 2;  // 0..1  (M half)
  const int wc = wave & 3;   // 0..3  (N quarter)
  const int frow = lane & 15;
  const int jb = lane >> 4;  // 0..3
  const int sw = frow & 7;   // XOR swizzle key
  const int bn = blockIdx.x, bm = blockIdx.y;
  const size_t rowA0 = (size_t)bm * 256;
  const size_t rowB0 = (size_t)bn * 256;

  f32x4 acc[8][4] = {};

  // stage one half-tile (h=0/1 -> rows h*128..h*128+127) of K-tile `ktile`.
  // LDS dest linear (wave-uniform base + lane*16); XOR swizzle applied to the
  // GLOBAL source chunk (m173 pattern).
  auto stage = [&](const unsigned short* __restrict__ G, size_t row0,
                   unsigned short* dst, int h, int ktile) {
    const int kt = (ktile < 64 ? ktile : 0) << 6;  // clamp: tiles >=64 load k=0, never read
#pragma unroll
    for (int l = 0; l < 2; ++l) {
      const int c = (l << 9) + tid;          // 0..1023
      const int r = c >> 3;                  // row within half: 0..127
      const int jg = (c & 7) ^ (r & 7);      // pre-swizzled global chunk
      gl2lds16(G + (row0 + (size_t)((h << 7) + r)) * K + kt + (jg << 3),
               dst + (h << 13) + (c << 3));
    }
  };

  // one 4-phase group; r0/r1/r2 rotate over m-steps 0..7 with 2-batch lookahead
  auto group = [&](int p, int gA, int gB) {
    const unsigned short* sAp = sA[p];
    const unsigned short* sBp = sB[p];
    unsigned short* sAn = (unsigned short*)sA[p ^ 1];
    unsigned short* sBn = (unsigned short*)sB[p];
    bf16x8 bq[4][2];
    bf16x8 r0[2], r1[2], r2[2];
    // ---- phase 0: burst = bq + r0..r2 (14 reads)
    RD_A(r0, 0);
    RD_B();
    RD_A(r1, 1);
    RD_A(r2, 2);
    stage(A, rowA0, sAn, 0, gA);
    BARX();
    __builtin_amdgcn_s_setprio(1);
    MF(0, r0);
    RD_A(r0, 3);
    MF(1, r1);
    __builtin_amdgcn_s_setprio(0);
    BARX();
    // ---- phase 1
    RD_A(r1, 4);
    stage(A, rowA0, sAn, 1, gA);
    BARX();
    __builtin_amdgcn_s_setprio(1);
    MF(2, r2);
    RD_A(r2, 5);
    MF(3, r0);
    __builtin_amdgcn_s_setprio(0);
    BARX();
    // ---- phase 2
    RD_A(r0, 6);
    stage(B, rowB0, sBn, 0, gB);
    BARX();
    __builtin_amdgcn_s_setprio(1);
    MF(4, r1);
    RD_A(r1, 7);
    MF(5, r2);
    __builtin_amdgcn_s_setprio(0);
    BARX();
    // ---- phase 3 (pure MFMA; single per-K-tile vmcnt before closing barrier)
    stage(B, rowB0, sBn, 1, gB);
    BARX();
    __builtin_amdgcn_s_setprio(1);
    MF(6, r0);
    MF(7, r1);
    __builtin_amdgcn_s_setprio(0);
    WAITV4();
    BARX();
  };

  // prologue: tile0 (B then A) -> buf0, B(1) -> buf1; vmcnt(4) leaves B(1)'s
  // 4 loads in flight (steady-state entry invariant).
  stage(B, rowB0, sB[0], 0, 0);
  stage(B, rowB0, sB[0], 1, 0);
  stage(A, rowA0, sA[0], 0, 0);
  stage(A, rowA0, sA[0], 1, 0);
  stage(B, rowB0, sB[1], 0, 1);
  stage(B, rowB0, sB[1], 1, 1);
  WAITV4();
  BARX();

#pragma unroll 1
  for (int i = 0; i < 32; ++i) {
    group(0, 2 * i + 1, 2 * i + 2);
    group(1, 2 * i + 2, 2 * i + 3);
  }

  // epilogue: C/D layout col = lane&15, row = (lane>>4)*4 + reg
  const int rbase = bm * 256 + (wr << 7) + (jb << 2);
  const int cbase = bn * 256 + (wc << 6) + frow;
#pragma unroll
  for (int m = 0; m < 8; ++m)
#pragma unroll
    for (int n = 0; n < 4; ++n) {
      float* cp = C + (size_t)(rbase + (m << 4)) * N + cbase + (n << 4);
#pragma unroll
      for (int r = 0; r < 4; ++r) cp[(size_t)r * N] = acc[m][n][r];
    }
}

// ---------------------------------------------------------------------------
// K4: per-row FWHT(4096) on fp32 output ; * SV * (1/64)
// ---------------------------------------------------------------------------
__global__ void __launch_bounds__(256) k_fwht_out(float* __restrict__ Y,
                                                  const float* __restrict__ SV) {
  __shared__ float lds[4224];
  const int t = threadIdx.x;
  const size_t row = blockIdx.x;
  float* yrow = Y + row * 4096;
  const float4* yr = (const float4*)yrow;
  float v[16];
#pragma unroll
  for (int q = 0; q < 4; ++q) {
    float4 a = yr[4 * t + q];
    v[4 * q + 0] = a.x;
    v[4 * q + 1] = a.y;
    v[4 * q + 2] = a.z;
    v[4 * q + 3] = a.w;
  }
  fwht16(v);  // bits 0-3
#pragma unroll
  for (int q = 0; q < 4; ++q) {
    int i0 = 16 * t + 4 * q;
    *(float4*)&lds[LP(i0)] = make_float4(v[4 * q], v[4 * q + 1], v[4 * q + 2], v[4 * q + 3]);
  }
  __syncthreads();
  const int b = ((t >> 4) << 8) | (t & 15);
#pragma unroll
  for (int j = 0; j < 16; ++j) { int i = b + 16 * j; v[j] = lds[LP(i)]; }
  fwht16(v);  // bits 4-7
#pragma unroll
  for (int j = 0; j < 16; ++j) { int i = b + 16 * j; lds[LP(i)] = v[j]; }
  __syncthreads();
#pragma unroll
  for (int j = 0; j < 16; ++j) { int i = t + 256 * j; v[j] = lds[LP(i)]; }
  fwht16(v);  // bits 8-11
#pragma unroll
  for (int j = 0; j < 16; ++j) {
    int i = t + 256 * j;
    yrow[i] = v[j] * SV[i] * 0.015625f;
  }
}

// ---------------------------------------------------------------------------
extern "C" void kernel_launch(void* const* d_in, const int* in_sizes, int n_in,
                              void* d_out, int out_size, void* d_ws, size_t ws_size,
                              hipStream_t stream) {
  const float* X     = (const float*)d_in[0];
  const float* SU    = (const float*)d_in[1];
  const float* SV    = (const float*)d_in[2];
  const float* G     = (const float*)d_in[3];
  const int*   Qidxs = (const int*)d_in[4];
  float* out = (float*)d_out;

  unsigned short* Xh = (unsigned short*)d_ws;
  unsigned short* Wh = Xh + (size_t)4096 * 4096;

  k_prep<<<4096 + 8192, 256, 0, stream>>>(X, SU, Xh, Qidxs, G, Wh);
  k_gemm_bt<<<dim3(16, 16), 512, 0, stream>>>(Xh, Wh, out);
  k_fwht_out<<<4096, 256, 0, stream>>>(out, SV);
}